// Round 1
// baseline (553.449 us; speedup 1.0000x reference)
//
#include <hip/hip_runtime.h>

// MaxwellFFNNModel: sequential scan over T=1024, B=2048 independent rows.
// Mapping: one wave (64 lanes) per batch row; lane = hidden unit.
// Per step: h1 = tanh(eps*W1r0 + gamma*W1r1 + b1)      (per-lane)
//           h2 = tanh(W2^T h1 + b2)                    (h1 broadcast via LDS,
//                                                       pk_fma with per-lane W2 column)
//           gdot = sum(h2*W3) + b3                     (DPP butterfly reduce)
//           gamma += dt*gdot;  sigma = 2.5*eps - 2*gamma

typedef float f2 __attribute__((ext_vector_type(2)));
typedef float f4 __attribute__((ext_vector_type(4)));

__device__ __forceinline__ float tanh_fast(float x) {
    // tanh(x) = 1 - 2/(e^{2x}+1); exp2 form. Saturates correctly for |x| large.
    float e = __builtin_amdgcn_exp2f(x * 2.885390081777927f); // 2*log2(e)
    float r = __builtin_amdgcn_rcpf(e + 1.0f);
    return fmaf(-2.0f, r, 1.0f);
}

template<int CTRL>
__device__ __forceinline__ float dpp_add(float v) {
    int m = __builtin_amdgcn_update_dpp(0, __float_as_int(v), CTRL, 0xF, 0xF, true);
    return v + __int_as_float(m);
}

// Full 64-lane sum, result broadcast (uniform) via readlane of lane 63.
__device__ __forceinline__ float wave_sum_bcast(float v) {
    v = dpp_add<0xB1>(v);   // quad_perm(1,0,3,2)  -> pairs
    v = dpp_add<0x4E>(v);   // quad_perm(2,3,0,1)  -> quads
    v = dpp_add<0x141>(v);  // row_half_mirror     -> 8
    v = dpp_add<0x140>(v);  // row_mirror          -> 16
    v = dpp_add<0x142>(v);  // row_bcast15         -> lane31/63 hold sum32
    v = dpp_add<0x143>(v);  // row_bcast31         -> lane63 holds sum64
    return __int_as_float(__builtin_amdgcn_readlane(__float_as_int(v), 63));
}

__global__ __launch_bounds__(256, 2) void maxwell_scan_kernel(
    const float* __restrict__ x,  const float* __restrict__ W1,
    const float* __restrict__ b1, const float* __restrict__ W2,
    const float* __restrict__ b2, const float* __restrict__ W3,
    const float* __restrict__ b3, float* __restrict__ out)
{
    __shared__ __align__(16) float lds_h1[4][64];   // wave-private h1 broadcast buffers
    const int lane = threadIdx.x & 63;
    const int warp = threadIdx.x >> 6;
    const int b    = (blockIdx.x << 2) + warp;      // batch row, 0..2047

    // Per-lane weights: column `lane` of each matrix.
    const float w1_0 = W1[lane];        // W1[0][lane]
    const float w1_1 = W1[64 + lane];   // W1[1][lane]
    const float b1j  = b1[lane];
    const float b2j  = b2[lane];
    const float w3j  = W3[lane];
    const float b3s  = b3[0];

    // W2 column `lane` as 32 packed pairs: w2p[i] = {W2[2i][lane], W2[2i+1][lane]}
    f2 w2p[32];
#pragma unroll
    for (int i = 0; i < 32; ++i) {
        w2p[i] = (f2){ W2[(2 * i) * 64 + lane], W2[(2 * i + 1) * 64 + lane] };
    }

    const f2* __restrict__ xrow = (const f2*)(x) + (size_t)b * 1024; // (eps,dt) pairs
    float*    __restrict__ orow = out + (size_t)b * 1024;
    float* h1s = lds_h1[warp];
    const f4* hv = (const f4*)h1s;

    float gamma = 0.0f;
    f2 vx = xrow[lane];                 // chunk 0: lane holds (eps,dt) of step lane

    for (int c = 0; c < 16; ++c) {
        f2 vx_next = vx;
        if (c < 15) vx_next = xrow[(c + 1) * 64 + lane];   // prefetch next chunk
        const float veps = vx.x, vdt = vx.y;
        float vsig = 0.0f;

#pragma unroll 4
        for (int k = 0; k < 64; ++k) {
            const float eps = __int_as_float(__builtin_amdgcn_readlane(__float_as_int(veps), k));
            const float dt  = __int_as_float(__builtin_amdgcn_readlane(__float_as_int(vdt),  k));

            // layer 1 (input = [eps, gamma], both wave-uniform)
            const float h1 = tanh_fast(fmaf(eps, w1_0, fmaf(gamma, w1_1, b1j)));
            h1s[lane] = h1;
            __builtin_amdgcn_wave_barrier();   // same-wave DS ops are in-order; fence compiler

            // layer 2: h2_j = sum_i h1[i]*W2[i][j]; LDS broadcast reads + packed FMA
            f2 acc0 = {0.f, 0.f}, acc1 = {0.f, 0.f}, acc2 = {0.f, 0.f}, acc3 = {0.f, 0.f};
#pragma unroll
            for (int q = 0; q < 16; q += 2) {
                f4 ha = hv[q];
                f4 hb = hv[q + 1];
                acc0 += (f2){ha.x, ha.y} * w2p[2 * q];
                acc1 += (f2){ha.z, ha.w} * w2p[2 * q + 1];
                acc2 += (f2){hb.x, hb.y} * w2p[2 * q + 2];
                acc3 += (f2){hb.z, hb.w} * w2p[2 * q + 3];
            }
            __builtin_amdgcn_wave_barrier();
            f2 s = (acc0 + acc1) + (acc2 + acc3);
            const float h2 = tanh_fast(s.x + s.y + b2j);

            // layer 3 + reduce: gamma_dot (uniform across lanes)
            const float gdot = wave_sum_bcast(h2 * w3j) + b3s;
            gamma = fmaf(dt, gdot, gamma);

            // sigma = E_inf*eps + E*(eps-gamma) = 2.5*eps - 2*gamma; park in lane k
            const float sig = fmaf(2.5f, eps, -2.0f * gamma);
            vsig = (lane == k) ? sig : vsig;
        }
        orow[c * 64 + lane] = vsig;     // coalesced 256B store per chunk
        vx = vx_next;
    }
}

extern "C" void kernel_launch(void* const* d_in, const int* in_sizes, int n_in,
                              void* d_out, int out_size, void* d_ws, size_t ws_size,
                              hipStream_t stream) {
    const float* x  = (const float*)d_in[0];
    const float* W1 = (const float*)d_in[1];
    const float* b1 = (const float*)d_in[2];
    const float* W2 = (const float*)d_in[3];
    const float* b2 = (const float*)d_in[4];
    const float* W3 = (const float*)d_in[5];
    const float* b3 = (const float*)d_in[6];
    float* out = (float*)d_out;
    (void)in_sizes; (void)n_in; (void)d_ws; (void)ws_size; (void)out_size;

    // B=2048 rows, one wave each; 4 waves/block -> 512 blocks (2 blocks/CU).
    maxwell_scan_kernel<<<512, 256, 0, stream>>>(x, W1, b1, W2, b2, W3, b3, out);
}

// Round 2
// 541.653 us; speedup vs baseline: 1.0218x; 1.0218x over previous
//
#include <hip/hip_runtime.h>

// MaxwellFFNNModel: sequential scan over T=1024, B=2048 independent rows.
// Mapping: one wave (64 lanes) per batch row; lane = hidden unit.
// Per step: h1 = tanh(eps*W1r0 + gamma*W1r1 + b1)      (per-lane)
//           h2 = tanh(W2^T h1 + b2)                    (h1 broadcast via LDS,
//                                                       packed FMA with per-lane W2 column)
//           gdot = sum(h2*W3) + b3                     (DPP butterfly reduce)
//           gamma += dt*gdot;  sigma = 2.5*eps - 2*gamma
//
// R1 lesson: VGPR_Count=52 proved W2 column was NOT register-resident
// (remat'd loads / AGPR shuffling on the critical chain). This version pins
// the 32 f2 W2 values to arch VGPRs with opaque asm, and hoists per-step
// scalar prep (readlane eps/dt, layer-1 partial) off the recurrent chain.

typedef float f2 __attribute__((ext_vector_type(2)));
typedef float f4 __attribute__((ext_vector_type(4)));

__device__ __forceinline__ float tanh_fast(float x) {
    // tanh(x) = 1 - 2/(e^{2x}+1); exp2 form. Saturates correctly for |x| large.
    float e = __builtin_amdgcn_exp2f(x * 2.885390081777927f); // 2*log2(e)
    float r = __builtin_amdgcn_rcpf(e + 1.0f);
    return fmaf(-2.0f, r, 1.0f);
}

template<int CTRL>
__device__ __forceinline__ float dpp_add(float v) {
    int m = __builtin_amdgcn_update_dpp(0, __float_as_int(v), CTRL, 0xF, 0xF, true);
    return v + __int_as_float(m);
}

// Full 64-lane sum, result broadcast (uniform) via readlane of lane 63.
__device__ __forceinline__ float wave_sum_bcast(float v) {
    v = dpp_add<0xB1>(v);   // quad_perm(1,0,3,2)  -> pairs
    v = dpp_add<0x4E>(v);   // quad_perm(2,3,0,1)  -> quads
    v = dpp_add<0x141>(v);  // row_half_mirror     -> 8
    v = dpp_add<0x140>(v);  // row_mirror          -> 16
    v = dpp_add<0x142>(v);  // row_bcast15         -> lane31/63 hold sum32
    v = dpp_add<0x143>(v);  // row_bcast31         -> lane63 holds sum64
    return __int_as_float(__builtin_amdgcn_readlane(__float_as_int(v), 63));
}

__device__ __forceinline__ float rl(float v, int k) {
    return __int_as_float(__builtin_amdgcn_readlane(__float_as_int(v), k));
}

__global__ __launch_bounds__(256, 2) void maxwell_scan_kernel(
    const float* __restrict__ x,  const float* __restrict__ W1,
    const float* __restrict__ b1, const float* __restrict__ W2,
    const float* __restrict__ b2, const float* __restrict__ W3,
    const float* __restrict__ b3, float* __restrict__ out)
{
    __shared__ __align__(16) float lds_h1[4][64];   // wave-private h1 broadcast buffers
    const int lane = threadIdx.x & 63;
    const int warp = threadIdx.x >> 6;
    const int b    = (blockIdx.x << 2) + warp;      // batch row, 0..2047

    // Per-lane weights: column `lane` of each matrix.
    const float w1_0 = W1[lane];        // W1[0][lane]
    const float w1_1 = W1[64 + lane];   // W1[1][lane]
    const float b1j  = b1[lane];
    const float b2j  = b2[lane];
    const float w3j  = W3[lane];
    const float b3s  = b3[0];

    // W2 column `lane` as 32 packed pairs: w2p[i] = {W2[2i][lane], W2[2i+1][lane]}
    f2 w2p[32];
#pragma unroll
    for (int i = 0; i < 32; ++i) {
        w2p[i] = (f2){ W2[(2 * i) * 64 + lane], W2[(2 * i + 1) * 64 + lane] };
    }
    // Pin to arch VGPRs: opaque to remat, "v" class forbids AGPR/scratch homes.
#pragma unroll
    for (int i = 0; i < 32; ++i) asm volatile("" : "+v"(w2p[i]));

    const f2* __restrict__ xrow = (const f2*)(x) + (size_t)b * 1024; // (eps,dt) pairs
    float*    __restrict__ orow = out + (size_t)b * 1024;
    float* h1s = lds_h1[warp];
    const f4* hv = (const f4*)h1s;

    float gamma = 0.0f;
    f2 vx = xrow[lane];                 // chunk 0: lane holds (eps,dt) of step lane

    for (int c = 0; c < 16; ++c) {
        f2 vx_next = vx;
        if (c < 15) vx_next = xrow[(c + 1) * 64 + lane];   // prefetch next chunk
        float vsig = 0.0f;

        for (int s = 0; s < 8; ++s) {          // 8 sub-chunks of 8 steps
            const int k0 = s * 8;
            // Batch scalar prep for 8 steps — independent ops, off the chain.
            float pk[8], dtk[8], sg[8];
#pragma unroll
            for (int t = 0; t < 8; ++t) {
                const float e = rl(vx.x, k0 + t);
                dtk[t] = rl(vx.y, k0 + t);
                pk[t]  = fmaf(e, w1_0, b1j);   // layer-1 partial (gamma added later)
                sg[t]  = 2.5f * e;             // sigma partial
            }

#pragma unroll
            for (int t = 0; t < 8; ++t) {
                // layer 1 (only gamma-dependent part is on the chain)
                const float h1 = tanh_fast(fmaf(gamma, w1_1, pk[t]));
                h1s[lane] = h1;
                __builtin_amdgcn_wave_barrier();   // same-wave DS ops in-order; fence compiler

                // layer 2: h2_j = sum_i h1[i]*W2[i][j]; LDS broadcast reads + packed FMA
                f2 acc0 = {0.f, 0.f}, acc1 = {0.f, 0.f}, acc2 = {0.f, 0.f}, acc3 = {0.f, 0.f};
#pragma unroll
                for (int q = 0; q < 16; q += 2) {
                    f4 ha = hv[q];
                    f4 hb = hv[q + 1];
                    acc0 += (f2){ha.x, ha.y} * w2p[2 * q];
                    acc1 += (f2){ha.z, ha.w} * w2p[2 * q + 1];
                    acc2 += (f2){hb.x, hb.y} * w2p[2 * q + 2];
                    acc3 += (f2){hb.z, hb.w} * w2p[2 * q + 3];
                }
                __builtin_amdgcn_wave_barrier();
                f2 sv = (acc0 + acc1) + (acc2 + acc3);
                const float h2 = tanh_fast(sv.x + sv.y + b2j);

                // layer 3 + reduce: gamma_dot (uniform across lanes)
                const float gdot = wave_sum_bcast(h2 * w3j) + b3s;
                gamma = fmaf(dtk[t], gdot, gamma);

                // sigma = 2.5*eps - 2*gamma; park in lane (k0+t)
                const float sig = fmaf(-2.0f, gamma, sg[t]);
                vsig = (lane == k0 + t) ? sig : vsig;
            }
        }
        orow[c * 64 + lane] = vsig;     // coalesced 256B store per chunk
        vx = vx_next;
    }
}

extern "C" void kernel_launch(void* const* d_in, const int* in_sizes, int n_in,
                              void* d_out, int out_size, void* d_ws, size_t ws_size,
                              hipStream_t stream) {
    const float* x  = (const float*)d_in[0];
    const float* W1 = (const float*)d_in[1];
    const float* b1 = (const float*)d_in[2];
    const float* W2 = (const float*)d_in[3];
    const float* b2 = (const float*)d_in[4];
    const float* W3 = (const float*)d_in[5];
    const float* b3 = (const float*)d_in[6];
    float* out = (float*)d_out;
    (void)in_sizes; (void)n_in; (void)d_ws; (void)ws_size; (void)out_size;

    // B=2048 rows, one wave each; 4 waves/block -> 512 blocks (2 blocks/CU).
    maxwell_scan_kernel<<<512, 256, 0, stream>>>(x, W1, b1, W2, b2, W3, b3, out);
}

// Round 4
// 482.549 us; speedup vs baseline: 1.1469x; 1.1225x over previous
//
#include <hip/hip_runtime.h>

// MaxwellFFNNModel: sequential scan over T=1024, B=2048 independent rows.
// Mapping: one wave (64 lanes) per batch row; lane = hidden unit.
// Per step: h1 = tanh(eps*W1r0 + gamma*W1r1 + b1)          (per-lane, f32)
//           h2 = tanh(W2^T h1 + b2)                        (f16 dot2: h1 pairs
//                broadcast via DPP-pack + 32 readlane SGPRs; W2 column resident
//                as 32 f16x2 VGPRs; v_dot2_f32_f16 w/ SGPR operand. NO LDS.)
//           gdot = sum(h2*W3) + b3                         (DPP butterfly reduce)
//           gamma += dt*gdot;  sigma = 2.5*eps - 2*gamma
//
// R3 lesson: DPP ctrl 0x111 is row_SHR:1 (lane n <- lane n-1, the prefix-sum
// direction). Pair-packing needs row_SHL:1 = 0x101 (lane n <- lane n+1).
// Row-boundary lanes (15/31/47/63) get bound_ctrl zeros but packd is only
// read at even lanes, all in-row. R1/R2 lesson: VGPR_Count=52/60 proved the
// allocator evicted W2 toward the 64-VGPR tier; amdgpu_waves_per_eu(2,2)
// states the honest budget (grid only supplies 2 waves/SIMD).

typedef float f2 __attribute__((ext_vector_type(2)));
typedef _Float16 h2v __attribute__((ext_vector_type(2)));

__device__ __forceinline__ float tanh_fast(float x) {
    // tanh(x) = 1 - 2/(e^{2x}+1); exp2 form. Saturates correctly for |x| large.
    float e = __builtin_amdgcn_exp2f(x * 2.885390081777927f); // 2*log2(e)
    float r = __builtin_amdgcn_rcpf(e + 1.0f);
    return fmaf(-2.0f, r, 1.0f);
}

template<int CTRL>
__device__ __forceinline__ float dpp_add(float v) {
    int m = __builtin_amdgcn_update_dpp(0, __float_as_int(v), CTRL, 0xF, 0xF, true);
    return v + __int_as_float(m);
}

// Full 64-lane sum, result broadcast (uniform) via readlane of lane 63.
__device__ __forceinline__ float wave_sum_bcast(float v) {
    v = dpp_add<0xB1>(v);   // quad_perm(1,0,3,2)  -> pairs
    v = dpp_add<0x4E>(v);   // quad_perm(2,3,0,1)  -> quads
    v = dpp_add<0x141>(v);  // row_half_mirror     -> 8
    v = dpp_add<0x140>(v);  // row_mirror          -> 16
    v = dpp_add<0x142>(v);  // row_bcast15         -> lane31/63 hold sum32
    v = dpp_add<0x143>(v);  // row_bcast31         -> lane63 holds sum64
    return __int_as_float(__builtin_amdgcn_readlane(__float_as_int(v), 63));
}

__device__ __forceinline__ float rl(float v, int k) {
    return __int_as_float(__builtin_amdgcn_readlane(__float_as_int(v), k));
}

__global__ __attribute__((amdgpu_flat_work_group_size(256, 256),
                          amdgpu_waves_per_eu(2, 2)))
void maxwell_scan_kernel(
    const float* __restrict__ x,  const float* __restrict__ W1,
    const float* __restrict__ b1, const float* __restrict__ W2,
    const float* __restrict__ b2, const float* __restrict__ W3,
    const float* __restrict__ b3, float* __restrict__ out)
{
    const int lane = threadIdx.x & 63;
    const int warp = threadIdx.x >> 6;
    const int b    = (blockIdx.x << 2) + warp;      // batch row, 0..2047

    // Per-lane weights: column `lane` of each matrix.
    const float w1_0 = W1[lane];        // W1[0][lane]
    const float w1_1 = W1[64 + lane];   // W1[1][lane]
    const float b1j  = b1[lane];
    const float b2j  = b2[lane];
    const float w3j  = W3[lane];
    const float b3s  = b3[0];

    // W2 column `lane` as 32 packed f16 pairs: w2i[i] = {W2[2i][lane], W2[2i+1][lane]}
    int w2i[32];
#pragma unroll
    for (int i = 0; i < 32; ++i) {
        h2v p = { (_Float16)W2[(2 * i) * 64 + lane],
                  (_Float16)W2[(2 * i + 1) * 64 + lane] };   // RNE casts
        w2i[i] = __builtin_bit_cast(int, p);
    }

    const f2* __restrict__ xrow = (const f2*)(x) + (size_t)b * 1024; // (eps,dt) pairs
    float*    __restrict__ orow = out + (size_t)b * 1024;

    float gamma = 0.0f;
    f2 vx = xrow[lane];                 // chunk 0: lane holds (eps,dt) of step lane

    for (int c = 0; c < 16; ++c) {
        f2 vx_next = vx;
        if (c < 15) vx_next = xrow[(c + 1) * 64 + lane];   // prefetch next chunk
        float vsig = 0.0f;

        for (int s = 0; s < 8; ++s) {          // 8 sub-chunks of 8 steps
            const int k0 = s * 8;
            // Batch scalar prep for 8 steps — independent ops, off the chain.
            float pk[8], dtk[8], sg[8];
#pragma unroll
            for (int t = 0; t < 8; ++t) {
                const float e = rl(vx.x, k0 + t);
                dtk[t] = rl(vx.y, k0 + t);
                pk[t]  = fmaf(e, w1_0, b1j);   // layer-1 partial (gamma added later)
                sg[t]  = 2.5f * e;             // sigma partial
            }

#pragma unroll
            for (int t = 0; t < 8; ++t) {
                // Keep W2 pinned in arch VGPRs every step (empty asm, no code).
                asm volatile("" : "+v"(w2i[0]), "+v"(w2i[1]), "+v"(w2i[2]), "+v"(w2i[3]),
                                  "+v"(w2i[4]), "+v"(w2i[5]), "+v"(w2i[6]), "+v"(w2i[7]),
                                  "+v"(w2i[8]), "+v"(w2i[9]), "+v"(w2i[10]), "+v"(w2i[11]),
                                  "+v"(w2i[12]), "+v"(w2i[13]), "+v"(w2i[14]), "+v"(w2i[15]));
                asm volatile("" : "+v"(w2i[16]), "+v"(w2i[17]), "+v"(w2i[18]), "+v"(w2i[19]),
                                  "+v"(w2i[20]), "+v"(w2i[21]), "+v"(w2i[22]), "+v"(w2i[23]),
                                  "+v"(w2i[24]), "+v"(w2i[25]), "+v"(w2i[26]), "+v"(w2i[27]),
                                  "+v"(w2i[28]), "+v"(w2i[29]), "+v"(w2i[30]), "+v"(w2i[31]));

                // layer 1 (only gamma-dependent part is on the chain)
                const float h1 = tanh_fast(fmaf(gamma, w1_1, pk[t]));

                // Pack h1 pairs: even lane 2i gets {h1[2i], h1[2i+1]} as f16x2.
                // row_shl:1 = 0x101: lane n receives lane n+1 (within 16-row).
                // (0x111 = row_shr:1 is the WRONG direction — R3 bug.)
                const int nb = __builtin_amdgcn_update_dpp(
                    0, __float_as_int(h1), 0x101, 0xF, 0xF, true);
                const int packd = __builtin_bit_cast(
                    int, __builtin_amdgcn_cvt_pkrtz(h1, __int_as_float(nb)));

                // layer 2: h2_j = sum_i h1[i]*W2[i][j]
                // 32 constant-lane readlanes -> uniform SGPRs; dot2 with SGPR src.
                float a0 = b2j, a1 = 0.f, a2 = 0.f, a3 = 0.f;
#pragma unroll
                for (int i = 0; i < 32; i += 4) {
                    const int s0 = __builtin_amdgcn_readlane(packd, 2 * i);
                    const int s1 = __builtin_amdgcn_readlane(packd, 2 * i + 2);
                    const int s2 = __builtin_amdgcn_readlane(packd, 2 * i + 4);
                    const int s3 = __builtin_amdgcn_readlane(packd, 2 * i + 6);
                    a0 = __builtin_amdgcn_fdot2(__builtin_bit_cast(h2v, w2i[i]),
                                                __builtin_bit_cast(h2v, s0), a0, false);
                    a1 = __builtin_amdgcn_fdot2(__builtin_bit_cast(h2v, w2i[i + 1]),
                                                __builtin_bit_cast(h2v, s1), a1, false);
                    a2 = __builtin_amdgcn_fdot2(__builtin_bit_cast(h2v, w2i[i + 2]),
                                                __builtin_bit_cast(h2v, s2), a2, false);
                    a3 = __builtin_amdgcn_fdot2(__builtin_bit_cast(h2v, w2i[i + 3]),
                                                __builtin_bit_cast(h2v, s3), a3, false);
                }
                const float h2 = tanh_fast((a0 + a1) + (a2 + a3));

                // layer 3 + reduce: gamma_dot (uniform across lanes)
                const float gdot = wave_sum_bcast(h2 * w3j) + b3s;
                gamma = fmaf(dtk[t], gdot, gamma);

                // sigma = 2.5*eps - 2*gamma; park in lane (k0+t)
                const float sig = fmaf(-2.0f, gamma, sg[t]);
                vsig = (lane == k0 + t) ? sig : vsig;
            }
        }
        orow[c * 64 + lane] = vsig;     // coalesced 256B store per chunk
        vx = vx_next;
    }
}

extern "C" void kernel_launch(void* const* d_in, const int* in_sizes, int n_in,
                              void* d_out, int out_size, void* d_ws, size_t ws_size,
                              hipStream_t stream) {
    const float* x  = (const float*)d_in[0];
    const float* W1 = (const float*)d_in[1];
    const float* b1 = (const float*)d_in[2];
    const float* W2 = (const float*)d_in[3];
    const float* b2 = (const float*)d_in[4];
    const float* W3 = (const float*)d_in[5];
    const float* b3 = (const float*)d_in[6];
    float* out = (float*)d_out;
    (void)in_sizes; (void)n_in; (void)d_ws; (void)ws_size; (void)out_size;

    // B=2048 rows, one wave each; 4 waves/block -> 512 blocks (2 blocks/CU),
    // 8 waves/CU = 2 waves/SIMD (matches amdgpu_waves_per_eu(2,2)).
    maxwell_scan_kernel<<<512, 256, 0, stream>>>(x, W1, b1, W2, b2, W3, b3, out);
}

// Round 8
// 427.186 us; speedup vs baseline: 1.2956x; 1.1296x over previous
//
#include <hip/hip_runtime.h>

// MaxwellFFNNModel: sequential scan over T=1024, B=2048 independent rows.
// Mapping: one wave (64 lanes) per batch row; lane = hidden unit.
// Per step: h1 = tanh(eps*W1r0 + gamma*W1r1 + b1)      (per-lane, f32)
//           h2 = tanh(W2^T h1 + b2)                    (h1 broadcast via LDS
//                f32 store + 16 uniform-address float4 reads (HW broadcast);
//                32 v_pk_fma_f32 with W2 column resident as 32 f2 VGPR pairs)
//           gdot = sum(h2*W3) + b3                     (DPP butterfly reduce)
//           gamma += dt*gdot;  sigma = 2.5*eps - 2*gamma
//
// R5/R7 lesson: short-store + int4-load LDS is TBAA-disjoint -> loads hoist
// above stores (may_alias on vector typedefs is silently IGNORED by clang).
// R1/R2's float-store + float4-load is TBAA-compatible and empirically
// passes -> this version returns to EXACTLY that access discipline.
// R6 lesson: never hand-write LDS addresses in asm.
// R4 lesson: readlane broadcast burns 2x issue slots; LDS broadcast is the
// right pipe. R1/R2/R4 lesson: allocator evicts W2 without
// amdgpu_waves_per_eu(2,2) (grid supplies only 2 waves/SIMD; tell it).

typedef float f2 __attribute__((ext_vector_type(2)));
typedef float f4 __attribute__((ext_vector_type(4)));

__device__ __forceinline__ float tanh_fast(float x) {
    // tanh(x) = 1 - 2/(e^{2x}+1); exp2 form. Saturates correctly for |x| large.
    float e = __builtin_amdgcn_exp2f(x * 2.885390081777927f); // 2*log2(e)
    float r = __builtin_amdgcn_rcpf(e + 1.0f);
    return fmaf(-2.0f, r, 1.0f);
}

template<int CTRL>
__device__ __forceinline__ float dpp_add(float v) {
    int m = __builtin_amdgcn_update_dpp(0, __float_as_int(v), CTRL, 0xF, 0xF, true);
    return v + __int_as_float(m);
}

// Full 64-lane sum, result broadcast (uniform) via readlane of lane 63.
__device__ __forceinline__ float wave_sum_bcast(float v) {
    v = dpp_add<0xB1>(v);   // quad_perm(1,0,3,2)  -> pairs
    v = dpp_add<0x4E>(v);   // quad_perm(2,3,0,1)  -> quads
    v = dpp_add<0x141>(v);  // row_half_mirror     -> 8
    v = dpp_add<0x140>(v);  // row_mirror          -> 16
    v = dpp_add<0x142>(v);  // row_bcast15         -> lane31/63 hold sum32
    v = dpp_add<0x143>(v);  // row_bcast31         -> lane63 holds sum64
    return __int_as_float(__builtin_amdgcn_readlane(__float_as_int(v), 63));
}

__device__ __forceinline__ float rl(float v, int k) {
    return __int_as_float(__builtin_amdgcn_readlane(__float_as_int(v), k));
}

__global__ __attribute__((amdgpu_flat_work_group_size(256, 256),
                          amdgpu_waves_per_eu(2, 2)))
void maxwell_scan_kernel(
    const float* __restrict__ x,  const float* __restrict__ W1,
    const float* __restrict__ b1, const float* __restrict__ W2,
    const float* __restrict__ b2, const float* __restrict__ W3,
    const float* __restrict__ b3, float* __restrict__ out)
{
    __shared__ __align__(16) float lds_h1[4][64];   // wave-private h1 broadcast buffers
    const int lane = threadIdx.x & 63;
    const int warp = threadIdx.x >> 6;
    const int b    = (blockIdx.x << 2) + warp;      // batch row, 0..2047

    // Per-lane weights: column `lane` of each matrix.
    const float w1_0 = W1[lane];        // W1[0][lane]
    const float w1_1 = W1[64 + lane];   // W1[1][lane]
    const float b1j  = b1[lane];
    const float b2j  = b2[lane];
    const float w3j  = W3[lane];
    const float b3s  = b3[0];

    // W2 column `lane` as 32 packed f32 pairs: w2p[i] = {W2[2i][lane], W2[2i+1][lane]}
    f2 w2p[32];
#pragma unroll
    for (int i = 0; i < 32; ++i) {
        w2p[i] = (f2){ W2[(2 * i) * 64 + lane], W2[(2 * i + 1) * 64 + lane] };
    }

    // LDS pointers: plain, non-restrict, float/float4 (R1-proven TBAA-safe).
    float* h1s = lds_h1[warp];
    const f4* hv = (const f4*)h1s;

    const f2* __restrict__ xrow = (const f2*)(x) + (size_t)b * 1024; // (eps,dt) pairs
    float*    __restrict__ orow = out + (size_t)b * 1024;

    float gamma = 0.0f;
    f2 vx = xrow[lane];                 // chunk 0: lane holds (eps,dt) of step lane

    for (int c = 0; c < 16; ++c) {
        f2 vx_next = vx;
        if (c < 15) vx_next = xrow[(c + 1) * 64 + lane];   // prefetch next chunk
        float vsig = 0.0f;

        for (int s = 0; s < 8; ++s) {          // 8 sub-chunks of 8 steps
            const int k0 = s * 8;
            // Batch scalar prep for 8 steps — independent ops, off the chain.
            float pk[8], dtk[8], sg[8];
#pragma unroll
            for (int t = 0; t < 8; ++t) {
                const float e = rl(vx.x, k0 + t);
                dtk[t] = rl(vx.y, k0 + t);
                pk[t]  = fmaf(e, w1_0, b1j);   // layer-1 partial (gamma added later)
                sg[t]  = 2.5f * e;             // sigma partial
            }

            // Keep W2 pinned in arch VGPRs (empty asm, once per sub-chunk).
            asm volatile("" : "+v"(w2p[0]), "+v"(w2p[1]), "+v"(w2p[2]), "+v"(w2p[3]),
                              "+v"(w2p[4]), "+v"(w2p[5]), "+v"(w2p[6]), "+v"(w2p[7]),
                              "+v"(w2p[8]), "+v"(w2p[9]), "+v"(w2p[10]), "+v"(w2p[11]),
                              "+v"(w2p[12]), "+v"(w2p[13]), "+v"(w2p[14]), "+v"(w2p[15]));
            asm volatile("" : "+v"(w2p[16]), "+v"(w2p[17]), "+v"(w2p[18]), "+v"(w2p[19]),
                              "+v"(w2p[20]), "+v"(w2p[21]), "+v"(w2p[22]), "+v"(w2p[23]),
                              "+v"(w2p[24]), "+v"(w2p[25]), "+v"(w2p[26]), "+v"(w2p[27]),
                              "+v"(w2p[28]), "+v"(w2p[29]), "+v"(w2p[30]), "+v"(w2p[31]));

#pragma unroll
            for (int t = 0; t < 8; ++t) {
                // layer 1 (only gamma-dependent part is on the chain)
                const float h1 = tanh_fast(fmaf(gamma, w1_1, pk[t]));
                h1s[lane] = h1;
                __builtin_amdgcn_wave_barrier();   // same-wave DS ops in-order; fence compiler

                // layer 2: h2_j = sum_i h1[i]*W2[i][j]; uniform float4 reads
                // (HW broadcast, conflict-free) + packed f32 FMA.
                f2 acc0 = {0.f, 0.f}, acc1 = {0.f, 0.f}, acc2 = {0.f, 0.f}, acc3 = {0.f, 0.f};
#pragma unroll
                for (int q = 0; q < 16; q += 2) {
                    f4 ha = hv[q];
                    f4 hb = hv[q + 1];
                    acc0 += (f2){ha.x, ha.y} * w2p[2 * q];
                    acc1 += (f2){ha.z, ha.w} * w2p[2 * q + 1];
                    acc2 += (f2){hb.x, hb.y} * w2p[2 * q + 2];
                    acc3 += (f2){hb.z, hb.w} * w2p[2 * q + 3];
                }
                __builtin_amdgcn_wave_barrier();
                f2 sv = (acc0 + acc1) + (acc2 + acc3);
                const float h2 = tanh_fast(sv.x + sv.y + b2j);

                // layer 3 + reduce: gamma_dot (uniform across lanes)
                const float gdot = wave_sum_bcast(h2 * w3j) + b3s;
                gamma = fmaf(dtk[t], gdot, gamma);

                // sigma = 2.5*eps - 2*gamma; park in lane (k0+t)
                const float sig = fmaf(-2.0f, gamma, sg[t]);
                vsig = (lane == k0 + t) ? sig : vsig;
            }
        }
        orow[c * 64 + lane] = vsig;     // coalesced 256B store per chunk
        vx = vx_next;
    }
}

extern "C" void kernel_launch(void* const* d_in, const int* in_sizes, int n_in,
                              void* d_out, int out_size, void* d_ws, size_t ws_size,
                              hipStream_t stream) {
    const float* x  = (const float*)d_in[0];
    const float* W1 = (const float*)d_in[1];
    const float* b1 = (const float*)d_in[2];
    const float* W2 = (const float*)d_in[3];
    const float* b2 = (const float*)d_in[4];
    const float* W3 = (const float*)d_in[5];
    const float* b3 = (const float*)d_in[6];
    float* out = (float*)d_out;
    (void)in_sizes; (void)n_in; (void)d_ws; (void)ws_size; (void)out_size;

    // B=2048 rows, one wave each; 4 waves/block -> 512 blocks (2 blocks/CU),
    // 8 waves/CU = 2 waves/SIMD (matches amdgpu_waves_per_eu(2,2)).
    maxwell_scan_kernel<<<512, 256, 0, stream>>>(x, W1, b1, W2, b2, W3, b3, out);
}

// Round 9
// 420.914 us; speedup vs baseline: 1.3149x; 1.0149x over previous
//
#include <hip/hip_runtime.h>

// MaxwellFFNNModel: sequential scan over T=1024, B=2048 independent rows.
// Mapping: one wave (64 lanes) per batch row.
// Layer 1: lane j computes h1_j = tanh(eps*W1[0][j] + gamma*W1[1][j] + b1[j]).
// Layer 2 (split-K-by-4): lane L=4o+k computes partials of outputs
//   {o,o+16,o+32,o+48} over K-slice i in [16k,16k+16):
//   - h1 staged in LDS (f32 store, float4 reads: R1/R8-proven TBAA discipline)
//   - each lane reads ONLY its 64B slice = 4 ds_read_b128 (vs 16 broadcast
//     reads in R8) -> DS ops/step 17 -> 5, attacking the per-CU DS-pipe
//     contention (~550 cyc/CU-step in R8) and chain latency
//   - 32 v_pk_fma_f32 (h1 pairs x W2 pairs), 2-level quad DPP reduce,
//     3-cndmask select (m=k) -> lane holds h2 for j = o+16k (bijection)
// Layer 3: gdot = wave_sum(h2*W3[jsel]) + b3 (DPP butterfly, order-free)
// gamma += dt*gdot;  sigma = 2.5*eps - 2*gamma
//
// R8 lesson: VALU work fixed (640 issue-cyc/SIMD-step) but wall stuck at
// 970 cyc/step -- LDS pipe (8 waves x 17 DS ops on one CU pipe) + 120cyc
// read latency on the serial chain is the co-bottleneck. This round: 5 DS ops.
// R5/R7 lesson: LDS accesses stay float/float4 typed (TBAA); no restrict.
// R6 lesson: no hand-written LDS addresses in asm.
// R1/R2/R4 lesson: amdgpu_waves_per_eu(2,2) required for W2 VGPR residency.

typedef float f2 __attribute__((ext_vector_type(2)));
typedef float f4 __attribute__((ext_vector_type(4)));

__device__ __forceinline__ float tanh_fast(float x) {
    // tanh(x) = 1 - 2/(e^{2x}+1); exp2 form. Saturates correctly for |x| large.
    float e = __builtin_amdgcn_exp2f(x * 2.885390081777927f); // 2*log2(e)
    float r = __builtin_amdgcn_rcpf(e + 1.0f);
    return fmaf(-2.0f, r, 1.0f);
}

template<int CTRL>
__device__ __forceinline__ float dpp_add(float v) {
    int m = __builtin_amdgcn_update_dpp(0, __float_as_int(v), CTRL, 0xF, 0xF, true);
    return v + __int_as_float(m);
}

// Sum over the 4 lanes of each quad; every lane of the quad gets the sum.
__device__ __forceinline__ float quad_sum(float v) {
    v = dpp_add<0xB1>(v);   // quad_perm(1,0,3,2): L ^ 1
    v = dpp_add<0x4E>(v);   // quad_perm(2,3,0,1): L ^ 2
    return v;
}

// Full 64-lane sum, result broadcast (uniform) via readlane of lane 63.
__device__ __forceinline__ float wave_sum_bcast(float v) {
    v = dpp_add<0xB1>(v);   // pairs
    v = dpp_add<0x4E>(v);   // quads
    v = dpp_add<0x141>(v);  // row_half_mirror -> 8
    v = dpp_add<0x140>(v);  // row_mirror      -> 16
    v = dpp_add<0x142>(v);  // row_bcast15     -> lane31/63 hold sum32
    v = dpp_add<0x143>(v);  // row_bcast31     -> lane63 holds sum64
    return __int_as_float(__builtin_amdgcn_readlane(__float_as_int(v), 63));
}

__device__ __forceinline__ float rl(float v, int k) {
    return __int_as_float(__builtin_amdgcn_readlane(__float_as_int(v), k));
}

__global__ __attribute__((amdgpu_flat_work_group_size(256, 256),
                          amdgpu_waves_per_eu(2, 2)))
void maxwell_scan_kernel(
    const float* __restrict__ x,  const float* __restrict__ W1,
    const float* __restrict__ b1, const float* __restrict__ W2,
    const float* __restrict__ b2, const float* __restrict__ W3,
    const float* __restrict__ b3, float* __restrict__ out)
{
    __shared__ __align__(16) float lds_h1[4][64];   // wave-private h1 buffers
    const int lane = threadIdx.x & 63;
    const int warp = threadIdx.x >> 6;
    const int b    = (blockIdx.x << 2) + warp;      // batch row, 0..2047

    const int o = lane >> 2;          // output base index, 0..15
    const int k = lane & 3;           // K-chunk, 0..3
    const int jsel = o + 16 * k;      // this lane's final h2 index (bijection)

    // Layer-1 weights: lane = hidden unit.
    const float w1_0 = W1[lane];
    const float w1_1 = W1[64 + lane];
    const float b1j  = b1[lane];
    // Layer-2/3 per-lane constants at the PERMUTED output index.
    const float b2s  = b2[jsel];
    const float w3s  = W3[jsel];
    const float b3s  = b3[0];

    // W2 slice for this lane: w2r[m][p] = {W2[i0][o+16m], W2[i0+1][o+16m]},
    // i0 = 16k+2p. 32 f2 = 64 VGPRs, resident (waves_per_eu(2,2)).
    f2 w2r[4][8];
#pragma unroll
    for (int m = 0; m < 4; ++m) {
#pragma unroll
        for (int p = 0; p < 8; ++p) {
            const int i0 = 16 * k + 2 * p;
            const int j  = o + 16 * m;
            w2r[m][p] = (f2){ W2[i0 * 64 + j], W2[(i0 + 1) * 64 + j] };
        }
    }

    // LDS pointers: plain, non-restrict, float/float4 (R1/R8-proven TBAA-safe).
    float* h1s = lds_h1[warp];
    const f4* hv = (const f4*)h1s + (k << 2);   // this lane's 64B slice

    const f2* __restrict__ xrow = (const f2*)(x) + (size_t)b * 1024; // (eps,dt)
    float*    __restrict__ orow = out + (size_t)b * 1024;

    float gamma = 0.0f;
    f2 vx = xrow[lane];                 // chunk 0: lane holds (eps,dt) of step lane

    for (int c = 0; c < 16; ++c) {
        f2 vx_next = vx;
        if (c < 15) vx_next = xrow[(c + 1) * 64 + lane];   // prefetch next chunk
        float vsig = 0.0f;

        for (int s = 0; s < 8; ++s) {          // 8 sub-chunks of 8 steps
            const int k0 = s * 8;
            // Batch scalar prep for 8 steps — independent ops, off the chain.
            float pk[8], dtk[8], sg[8];
#pragma unroll
            for (int t = 0; t < 8; ++t) {
                const float e = rl(vx.x, k0 + t);
                dtk[t] = rl(vx.y, k0 + t);
                pk[t]  = fmaf(e, w1_0, b1j);   // layer-1 partial (gamma added later)
                sg[t]  = 2.5f * e;             // sigma partial
            }

            // Keep W2 pinned in arch VGPRs (empty asm, once per sub-chunk).
            asm volatile("" : "+v"(w2r[0][0]), "+v"(w2r[0][1]), "+v"(w2r[0][2]), "+v"(w2r[0][3]),
                              "+v"(w2r[0][4]), "+v"(w2r[0][5]), "+v"(w2r[0][6]), "+v"(w2r[0][7]),
                              "+v"(w2r[1][0]), "+v"(w2r[1][1]), "+v"(w2r[1][2]), "+v"(w2r[1][3]),
                              "+v"(w2r[1][4]), "+v"(w2r[1][5]), "+v"(w2r[1][6]), "+v"(w2r[1][7]));
            asm volatile("" : "+v"(w2r[2][0]), "+v"(w2r[2][1]), "+v"(w2r[2][2]), "+v"(w2r[2][3]),
                              "+v"(w2r[2][4]), "+v"(w2r[2][5]), "+v"(w2r[2][6]), "+v"(w2r[2][7]),
                              "+v"(w2r[3][0]), "+v"(w2r[3][1]), "+v"(w2r[3][2]), "+v"(w2r[3][3]),
                              "+v"(w2r[3][4]), "+v"(w2r[3][5]), "+v"(w2r[3][6]), "+v"(w2r[3][7]));

#pragma unroll
            for (int t = 0; t < 8; ++t) {
                // layer 1 (only gamma-dependent part is on the chain)
                const float h1 = tanh_fast(fmaf(gamma, w1_1, pk[t]));
                h1s[lane] = h1;
                __builtin_amdgcn_wave_barrier();   // same-wave DS in-order; fence compiler

                // layer 2, split-K: 4 ds_read_b128 of this lane's slice,
                // 32 v_pk_fma_f32 into 4 f2 accumulators (one per output m).
                f2 a0 = {0.f, 0.f}, a1 = {0.f, 0.f}, a2 = {0.f, 0.f}, a3 = {0.f, 0.f};
#pragma unroll
                for (int q = 0; q < 4; ++q) {
                    const f4 h4 = hv[q];
                    const f2 hlo = (f2){h4.x, h4.y};
                    const f2 hhi = (f2){h4.z, h4.w};
                    a0 += hlo * w2r[0][2 * q];  a0 += hhi * w2r[0][2 * q + 1];
                    a1 += hlo * w2r[1][2 * q];  a1 += hhi * w2r[1][2 * q + 1];
                    a2 += hlo * w2r[2][2 * q];  a2 += hhi * w2r[2][2 * q + 1];
                    a3 += hlo * w2r[3][2 * q];  a3 += hhi * w2r[3][2 * q + 1];
                }
                __builtin_amdgcn_wave_barrier();

                // Horizontal + quad reduction (sums K-chunks across the quad).
                float s0 = quad_sum(a0.x + a0.y);
                float s1 = quad_sum(a1.x + a1.y);
                float s2 = quad_sum(a2.x + a2.y);
                float s3 = quad_sum(a3.x + a3.y);
                // Select m = k: lane keeps output jsel = o + 16k.
                const float t01 = (k & 1) ? s1 : s0;
                const float t23 = (k & 1) ? s3 : s2;
                const float pre = (k & 2) ? t23 : t01;
                const float h2 = tanh_fast(pre + b2s);

                // layer 3 + reduce: gamma_dot (uniform across lanes;
                // DPP tree sum is permutation-invariant).
                const float gdot = wave_sum_bcast(h2 * w3s) + b3s;
                gamma = fmaf(dtk[t], gdot, gamma);

                // sigma = 2.5*eps - 2*gamma; park in lane (k0+t)
                const float sig = fmaf(-2.0f, gamma, sg[t]);
                vsig = (lane == k0 + t) ? sig : vsig;
            }
        }
        orow[c * 64 + lane] = vsig;     // coalesced 256B store per chunk
        vx = vx_next;
    }
}

extern "C" void kernel_launch(void* const* d_in, const int* in_sizes, int n_in,
                              void* d_out, int out_size, void* d_ws, size_t ws_size,
                              hipStream_t stream) {
    const float* x  = (const float*)d_in[0];
    const float* W1 = (const float*)d_in[1];
    const float* b1 = (const float*)d_in[2];
    const float* W2 = (const float*)d_in[3];
    const float* b2 = (const float*)d_in[4];
    const float* W3 = (const float*)d_in[5];
    const float* b3 = (const float*)d_in[6];
    float* out = (float*)d_out;
    (void)in_sizes; (void)n_in; (void)d_ws; (void)ws_size; (void)out_size;

    // B=2048 rows, one wave each; 4 waves/block -> 512 blocks (2 blocks/CU),
    // 8 waves/CU = 2 waves/SIMD (matches amdgpu_waves_per_eu(2,2)).
    maxwell_scan_kernel<<<512, 256, 0, stream>>>(x, W1, b1, W2, b2, W3, b3, out);
}